// Round 22
// baseline (115.898 us; speedup 1.0000x reference)
//
#include <hip/hip_runtime.h>
#include <hip/hip_bf16.h>

#define BATCH 16
#define HW 50176          // 224*224
#define HID 256
#define K 64
#define NREP 16           // den/num accumulator replicas (contention 392 -> 24.5 per address)

// output layout (floats): transformed [0, 2408448) | m [2408448, 53788672) | palette [53788672, +3072)
#define OUT_T_OFF 0
#define OUT_M_OFF 2408448
#define OUT_P_OFF 53788672

typedef short bf16x8 __attribute__((ext_vector_type(8)));
typedef float f32x4  __attribute__((ext_vector_type(4)));
typedef float f32x2  __attribute__((ext_vector_type(2)));

// Kernel A: MLP via MFMA + softmax + den/num reduction (replicated atomics) + transposed
// m store. Weights converted/packed in-kernel during LDS staging (prep kernel eliminated):
//   - W2 fp32 -> bf16 via packed RN converts (bit-identical to prior prep path)
//   - W1+b1 packed as hid-pairs directly from global (L2-hot)
__global__ __launch_bounds__(256, 4) void colorcnn_mlp_softmax(
    const float* __restrict__ img, const float* __restrict__ W1,
    const float* __restrict__ b1, const float* __restrict__ W2,
    float* __restrict__ m_out, float* __restrict__ acc_ws)
{
    __shared__ int4 lds[2304];       // [0,2048): w2 bf16 swizzled, later reused as m-tile; [2048,2304): w1pp
    __shared__ float sred[4][256];   // per-wave den/num partials

    const int t = threadIdx.x;
    {
        const float4* w2f4 = (const float4*)W2;
#pragma unroll
        for (int q = 0; q < 8; ++q) {
            const int i = t + q * 256;           // unit i covers W2[8i .. 8i+7]
            const int n = i >> 5, s = i & 31;
            const float4 a = w2f4[i * 2];
            const float4 c = w2f4[i * 2 + 1];
            union { int4 v; unsigned int u[4]; } un;
            __hip_bfloat162 p0 = __float22bfloat162_rn(float2{a.x, a.y});
            __hip_bfloat162 p1 = __float22bfloat162_rn(float2{a.z, a.w});
            __hip_bfloat162 p2 = __float22bfloat162_rn(float2{c.x, c.y});
            __hip_bfloat162 p3 = __float22bfloat162_rn(float2{c.z, c.w});
            un.u[0] = *(unsigned int*)&p0;
            un.u[1] = *(unsigned int*)&p1;
            un.u[2] = *(unsigned int*)&p2;
            un.u[3] = *(unsigned int*)&p3;
            lds[n * 32 + (s ^ (n & 7))] = un.v;
        }
        // w1pp pack: pair q: even unit {w0a,w0b,w1a,w1b}, odd unit {w2a,w2b,ba,bb}
        const int q = t >> 1;
        float4 u;
        if ((t & 1) == 0) u = make_float4(W1[6 * q + 0], W1[6 * q + 3], W1[6 * q + 1], W1[6 * q + 4]);
        else              u = make_float4(W1[6 * q + 2], W1[6 * q + 5], b1[2 * q], b1[2 * q + 1]);
        *(float4*)&lds[2048 + t] = u;
    }
    __syncthreads();

    const int b    = blockIdx.y;
    const int pb   = blockIdx.x * 128;
    const int w    = t >> 6;
    const int lane = t & 63;
    const int l15  = lane & 15;
    const int lg   = lane >> 4;
    const int pwb  = pb + w * 32;
    const int x7   = l15 & 7;

    const float* ip = img + (size_t)b * 3 * HW;

    float rr[2], gg[2], uu[2];
#pragma unroll
    for (int s = 0; s < 2; ++s) {
        const int px = pwb + s * 16 + l15;
        rr[s] = ip[px]; gg[s] = ip[HW + px]; uu[s] = ip[2 * HW + px];
    }

    f32x4 acc[2][4];
#pragma unroll
    for (int s = 0; s < 2; ++s)
#pragma unroll
        for (int ni = 0; ni < 4; ++ni)
            acc[s][ni] = (f32x4){0.f, 0.f, 0.f, 0.f};

    const float4* w1base = (const float4*)&lds[2048 + lg * 8];

#pragma unroll
    for (int c = 0; c < 8; ++c) {
        union { bf16x8 v; unsigned int u[4]; } ua0, ua1;
#pragma unroll
        for (int p = 0; p < 4; ++p) {          // hid pair = c*16 + lg*4 + p
            const float4 uA = w1base[c * 32 + p * 2];       // {w0a,w0b,w1a,w1b}
            const float4 uB = w1base[c * 32 + p * 2 + 1];   // {w2a,w2b,ba,bb}
            const f32x2 wA0 = {uA.x, uA.y};
            const f32x2 wA1 = {uA.z, uA.w};
            const f32x2 wB0 = {uB.x, uB.y};
            const f32x2 bb2 = {uB.z, uB.w};
            const f32x2 z2  = {0.f, 0.f};

            f32x2 h0 = bb2, h1 = bb2;
            {
                const f32x2 r0 = {rr[0], rr[0]}, g0 = {gg[0], gg[0]}, u0 = {uu[0], uu[0]};
                h0 = r0 * wA0 + h0; h0 = g0 * wA1 + h0; h0 = u0 * wB0 + h0;
                h0 = __builtin_elementwise_max(h0, z2);
            }
            {
                const f32x2 r1 = {rr[1], rr[1]}, g1 = {gg[1], gg[1]}, u1 = {uu[1], uu[1]};
                h1 = r1 * wA0 + h1; h1 = g1 * wA1 + h1; h1 = u1 * wB0 + h1;
                h1 = __builtin_elementwise_max(h1, z2);
            }
            __hip_bfloat162 c0 = __float22bfloat162_rn(float2{h0.x, h0.y});
            __hip_bfloat162 c1 = __float22bfloat162_rn(float2{h1.x, h1.y});
            ua0.u[p] = *(unsigned int*)&c0;
            ua1.u[p] = *(unsigned int*)&c1;
        }
        const int sw = (c * 4 + lg) ^ x7;
#pragma unroll
        for (int ni = 0; ni < 4; ++ni) {
            const bf16x8 bf = *(const bf16x8*)&lds[(ni * 16 + l15) * 32 + sw];
            acc[0][ni] = __builtin_amdgcn_mfma_f32_16x16x32_bf16(ua0.v, bf, acc[0][ni], 0, 0, 0);
            acc[1][ni] = __builtin_amdgcn_mfma_f32_16x16x32_bf16(ua1.v, bf, acc[1][ni], 0, 0, 0);
        }
    }

    // Softmax over n=64 per pixel (no max-subtract; logits bounded, fp32 exp safe).
#pragma unroll
    for (int s = 0; s < 2; ++s) {
#pragma unroll
        for (int reg = 0; reg < 4; ++reg) {
            const float v0 = __expf(acc[s][0][reg]);
            const float v1 = __expf(acc[s][1][reg]);
            const float v2 = __expf(acc[s][2][reg]);
            const float v3 = __expf(acc[s][3][reg]);
            float sm = (v0 + v1) + (v2 + v3);
            sm += __shfl_xor(sm, 1);
            sm += __shfl_xor(sm, 2);
            sm += __shfl_xor(sm, 4);
            sm += __shfl_xor(sm, 8);
            const float inv = __builtin_amdgcn_rcpf(sm);
            acc[s][0][reg] = v0 * inv; acc[s][1][reg] = v1 * inv;
            acc[s][2][reg] = v2 * inv; acc[s][3][reg] = v3 * inv;
        }
    }

    // ---- den/num reduction ----
    float red[16];   // [q*4+ni], q: 0=den 1=numR 2=numG 3=numB ; n = ni*16 + l15
#pragma unroll
    for (int i = 0; i < 16; ++i) red[i] = 0.f;
#pragma unroll
    for (int s = 0; s < 2; ++s) {
        const int pxb = pwb + s * 16 + lg * 4;
        const f32x4 rC = *(const f32x4*)&ip[pxb];
        const f32x4 gC = *(const f32x4*)&ip[HW + pxb];
        const f32x4 uC = *(const f32x4*)&ip[2 * HW + pxb];
#pragma unroll
        for (int ni = 0; ni < 4; ++ni) {
#pragma unroll
            for (int reg = 0; reg < 4; ++reg) {
                const float mv = acc[s][ni][reg];
                red[ni]      += mv;
                red[4 + ni]   = fmaf(rC[reg], mv, red[4 + ni]);
                red[8 + ni]   = fmaf(gC[reg], mv, red[8 + ni]);
                red[12 + ni]  = fmaf(uC[reg], mv, red[12 + ni]);
            }
        }
    }
#pragma unroll
    for (int i = 0; i < 16; ++i) {
        red[i] += __shfl_xor(red[i], 16);
        red[i] += __shfl_xor(red[i], 32);
    }
    if (lg == 0) {
#pragma unroll
        for (int ni = 0; ni < 4; ++ni) {
            const int n = ni * 16 + l15;
            sred[w][n]       = red[ni];
            sred[w][64 + n]  = red[4 + ni];
            sred[w][128 + n] = red[8 + ni];
            sred[w][192 + n] = red[12 + ni];
        }
    }
    __syncthreads();   // sred ready AND all MFMA reads of the w2 region complete

    {
        float* repl = acc_ws + (blockIdx.x & (NREP - 1)) * 4096;
        const int q = t >> 6, n = t & 63;
        const float v = sred[0][t] + sred[1][t] + sred[2][t] + sred[3][t];
        if (q == 0) atomicAdd(&repl[b * K + n], v);
        else        atomicAdd(&repl[1024 + (b * 3 + (q - 1)) * K + n], v);
    }

    // ---- m-tile: stage acc in LDS (reuse w2 region; stride 132), 512B-contiguous row stores ----
    float* mt = (float*)&lds[0];     // 64 rows x 132 floats = 33792 B
#pragma unroll
    for (int s = 0; s < 2; ++s)
#pragma unroll
        for (int ni = 0; ni < 4; ++ni) {
            const int n  = ni * 16 + l15;
            const int px = w * 32 + s * 16 + lg * 4;
            *(f32x4*)&mt[n * 132 + px] = acc[s][ni];
        }
    __syncthreads();

    float* mo = m_out + (size_t)b * K * HW + pb;
#pragma unroll
    for (int r = 0; r < 16; ++r) {
        const int n = w * 16 + r;
        const f32x2 v = *(const f32x2*)&mt[n * 132 + lane * 2];
        *(f32x2*)&mo[(size_t)n * HW + lane * 2] = v;
    }
}

// Kernel C: palette (sum NREP replicas, fused) + transformed = sum_k m * palette.
// 4 px/thread, f32x4. (v7 structure)
__global__ __launch_bounds__(256) void colorcnn_reconstruct(
    const float* __restrict__ m, const float* __restrict__ acc_ws,
    float* __restrict__ pal_out, float* __restrict__ t_out)
{
    __shared__ float pl[192];
    const int b    = blockIdx.x / 49;
    const int tile = blockIdx.x % 49;
    const int t    = threadIdx.x;

    if (t < 192) {
        const int c = t >> 6, k = t & 63;
        float dsum = 0.f, nsum = 0.f;
#pragma unroll
        for (int r = 0; r < NREP; ++r) {
            dsum += acc_ws[r * 4096 + b * K + k];
            nsum += acc_ws[r * 4096 + 1024 + (b * 3 + c) * K + k];
        }
        const float v = nsum / (dsum + 1e-8f);
        pl[t] = v;
        if (tile == 0) pal_out[b * 3 * K + t] = v;
    }
    __syncthreads();

    const int p = tile * 1024 + t * 4;
    const float* mp = m + (size_t)b * K * HW + p;
    f32x4 ar = {0.f, 0.f, 0.f, 0.f}, ag = ar, ab = ar;
#pragma unroll
    for (int k = 0; k < K; ++k) {
        const f32x4 mv = *(const f32x4*)&mp[(size_t)k * HW];
        const float pr = pl[k], pg = pl[K + k], pu = pl[2 * K + k];
#pragma unroll
        for (int j = 0; j < 4; ++j) {
            ar[j] = fmaf(mv[j], pr, ar[j]);
            ag[j] = fmaf(mv[j], pg, ag[j]);
            ab[j] = fmaf(mv[j], pu, ab[j]);
        }
    }
    float* to = t_out + (size_t)b * 3 * HW + p;
    *(f32x4*)&to[0]      = ar;
    *(f32x4*)&to[HW]     = ag;
    *(f32x4*)&to[2 * HW] = ab;
}

extern "C" void kernel_launch(void* const* d_in, const int* in_sizes, int n_in,
                              void* d_out, int out_size, void* d_ws, size_t ws_size,
                              hipStream_t stream) {
    const float* img = (const float*)d_in[0];
    const float* W1  = (const float*)d_in[1];
    const float* b1  = (const float*)d_in[2];
    const float* W2  = (const float*)d_in[3];

    float* out   = (float*)d_out;
    float* t_out = out + OUT_T_OFF;
    float* m_out = out + OUT_M_OFF;
    float* p_out = out + OUT_P_OFF;

    float* acc_ws = (float*)d_ws;    // NREP x 4096 floats

    hipMemsetAsync(acc_ws, 0, NREP * 4096 * sizeof(float), stream);
    colorcnn_mlp_softmax<<<dim3(HW / 128, BATCH), 256, 0, stream>>>(img, W1, b1, W2, m_out, acc_ws);
    colorcnn_reconstruct<<<BATCH * 49, 256, 0, stream>>>(m_out, acc_ws, p_out, t_out);
}

// Round 23
// 111.295 us; speedup vs baseline: 1.0414x; 1.0414x over previous
//
#include <hip/hip_runtime.h>
#include <hip/hip_bf16.h>

#define BATCH 16
#define HW 50176          // 224*224
#define HID 256
#define K 64
#define NREP 16           // den/num accumulator replicas (contention 392 -> 24.5 per address)

// output layout (floats): transformed [0, 2408448) | m [2408448, 53788672) | palette [53788672, +3072)
#define OUT_T_OFF 0
#define OUT_M_OFF 2408448
#define OUT_P_OFF 53788672

// workspace layout (floats):
//   acc replicas [0, 65536): NREP x { den[1024], num[3072] }
//   w1pp pair-packed float4 [65536, 66560)
//   w2b bf16 (16384 elems = 8192 floats) @ 66560
#define WS_ACC 0
#define WS_W1P 65536
#define WS_W2B 66560

typedef short bf16x8 __attribute__((ext_vector_type(8)));
typedef float f32x4  __attribute__((ext_vector_type(4)));
typedef float f32x2  __attribute__((ext_vector_type(2)));

static __device__ __forceinline__ ushort f2bf(float x) {
    union { __hip_bfloat16 h; ushort s; } u;
    u.h = __float2bfloat16(x);
    return u.s;
}

// Prep (16 blocks): block r zeroes replica r; blocks 0-7 convert a W2 slice to bf16;
// block 0 also packs W1+b1 as hid-PAIRS (SoA within pair).
__global__ __launch_bounds__(256) void colorcnn_prep(
    const float* __restrict__ W1, const float* __restrict__ b1,
    const float* __restrict__ W2, float* __restrict__ wsf,
    float4* __restrict__ w1pp, ushort* __restrict__ w2b)
{
    const int t = threadIdx.x;
    const int r = blockIdx.x;
    float* acc = wsf + WS_ACC + r * 4096;
#pragma unroll
    for (int q = 0; q < 16; ++q) acc[q * 256 + t] = 0.f;   // zero this replica
    if (r == 0) {
        const int q = t >> 1;
        if ((t & 1) == 0)
            w1pp[t] = make_float4(W1[6 * q + 0], W1[6 * q + 3], W1[6 * q + 1], W1[6 * q + 4]);
        else
            w1pp[t] = make_float4(W1[6 * q + 2], W1[6 * q + 5], b1[2 * q], b1[2 * q + 1]);
    }
    if (r < 8) {
#pragma unroll
        for (int q = 0; q < 8; ++q) {
            const int i = (r * 8 + q) * 256 + t;
            w2b[i] = f2bf(W2[i]);
        }
    }
}

// Kernel A: MLP via MFMA + softmax + den/num reduction (replicated atomics) + transposed m store.
// (v21 body verbatim; NREP=16.)
__global__ __launch_bounds__(256, 4) void colorcnn_mlp_softmax(
    const float* __restrict__ img, const int4* __restrict__ w1pp4,
    const ushort* __restrict__ w2b, float* __restrict__ m_out,
    float* __restrict__ acc_ws)
{
    __shared__ int4 lds[2304];       // [0,2048): w2b swizzled, later reused as m-tile; [2048,2304): w1pp
    __shared__ float sred[4][256];   // per-wave den/num partials

    const int t = threadIdx.x;
    const int4* w2b16 = (const int4*)w2b;
#pragma unroll
    for (int q = 0; q < 8; ++q) {
        const int i = t + q * 256;
        const int n = i >> 5, s = i & 31;
        lds[n * 32 + (s ^ (n & 7))] = w2b16[i];
    }
    lds[2048 + t] = w1pp4[t];        // linear pair-packed
    __syncthreads();

    const int b    = blockIdx.y;
    const int pb   = blockIdx.x * 128;
    const int w    = t >> 6;
    const int lane = t & 63;
    const int l15  = lane & 15;
    const int lg   = lane >> 4;
    const int pwb  = pb + w * 32;
    const int x7   = l15 & 7;

    const float* ip = img + (size_t)b * 3 * HW;

    float rr[2], gg[2], uu[2];
#pragma unroll
    for (int s = 0; s < 2; ++s) {
        const int px = pwb + s * 16 + l15;
        rr[s] = ip[px]; gg[s] = ip[HW + px]; uu[s] = ip[2 * HW + px];
    }

    f32x4 acc[2][4];
#pragma unroll
    for (int s = 0; s < 2; ++s)
#pragma unroll
        for (int ni = 0; ni < 4; ++ni)
            acc[s][ni] = (f32x4){0.f, 0.f, 0.f, 0.f};

    const float4* w1base = (const float4*)&lds[2048 + lg * 8];

#pragma unroll
    for (int c = 0; c < 8; ++c) {
        union { bf16x8 v; unsigned int u[4]; } ua0, ua1;
#pragma unroll
        for (int p = 0; p < 4; ++p) {          // hid pair = c*16 + lg*4 + p
            const float4 uA = w1base[c * 32 + p * 2];       // {w0a,w0b,w1a,w1b}
            const float4 uB = w1base[c * 32 + p * 2 + 1];   // {w2a,w2b,ba,bb}
            const f32x2 wA0 = {uA.x, uA.y};
            const f32x2 wA1 = {uA.z, uA.w};
            const f32x2 wB0 = {uB.x, uB.y};
            const f32x2 bb2 = {uB.z, uB.w};
            const f32x2 z2  = {0.f, 0.f};

            f32x2 h0 = bb2, h1 = bb2;
            {
                const f32x2 r0 = {rr[0], rr[0]}, g0 = {gg[0], gg[0]}, u0 = {uu[0], uu[0]};
                h0 = r0 * wA0 + h0; h0 = g0 * wA1 + h0; h0 = u0 * wB0 + h0;
                h0 = __builtin_elementwise_max(h0, z2);
            }
            {
                const f32x2 r1 = {rr[1], rr[1]}, g1 = {gg[1], gg[1]}, u1 = {uu[1], uu[1]};
                h1 = r1 * wA0 + h1; h1 = g1 * wA1 + h1; h1 = u1 * wB0 + h1;
                h1 = __builtin_elementwise_max(h1, z2);
            }
            __hip_bfloat162 c0 = __float22bfloat162_rn(float2{h0.x, h0.y});
            __hip_bfloat162 c1 = __float22bfloat162_rn(float2{h1.x, h1.y});
            ua0.u[p] = *(unsigned int*)&c0;
            ua1.u[p] = *(unsigned int*)&c1;
        }
        const int sw = (c * 4 + lg) ^ x7;
#pragma unroll
        for (int ni = 0; ni < 4; ++ni) {
            const bf16x8 bf = *(const bf16x8*)&lds[(ni * 16 + l15) * 32 + sw];
            acc[0][ni] = __builtin_amdgcn_mfma_f32_16x16x32_bf16(ua0.v, bf, acc[0][ni], 0, 0, 0);
            acc[1][ni] = __builtin_amdgcn_mfma_f32_16x16x32_bf16(ua1.v, bf, acc[1][ni], 0, 0, 0);
        }
    }

    // Softmax over n=64 per pixel (no max-subtract; logits bounded, fp32 exp safe).
#pragma unroll
    for (int s = 0; s < 2; ++s) {
#pragma unroll
        for (int reg = 0; reg < 4; ++reg) {
            const float v0 = __expf(acc[s][0][reg]);
            const float v1 = __expf(acc[s][1][reg]);
            const float v2 = __expf(acc[s][2][reg]);
            const float v3 = __expf(acc[s][3][reg]);
            float sm = (v0 + v1) + (v2 + v3);
            sm += __shfl_xor(sm, 1);
            sm += __shfl_xor(sm, 2);
            sm += __shfl_xor(sm, 4);
            sm += __shfl_xor(sm, 8);
            const float inv = __builtin_amdgcn_rcpf(sm);
            acc[s][0][reg] = v0 * inv; acc[s][1][reg] = v1 * inv;
            acc[s][2][reg] = v2 * inv; acc[s][3][reg] = v3 * inv;
        }
    }

    // ---- den/num reduction ----
    float red[16];   // [q*4+ni], q: 0=den 1=numR 2=numG 3=numB ; n = ni*16 + l15
#pragma unroll
    for (int i = 0; i < 16; ++i) red[i] = 0.f;
#pragma unroll
    for (int s = 0; s < 2; ++s) {
        const int pxb = pwb + s * 16 + lg * 4;
        const f32x4 rC = *(const f32x4*)&ip[pxb];
        const f32x4 gC = *(const f32x4*)&ip[HW + pxb];
        const f32x4 uC = *(const f32x4*)&ip[2 * HW + pxb];
#pragma unroll
        for (int ni = 0; ni < 4; ++ni) {
#pragma unroll
            for (int reg = 0; reg < 4; ++reg) {
                const float mv = acc[s][ni][reg];
                red[ni]      += mv;
                red[4 + ni]   = fmaf(rC[reg], mv, red[4 + ni]);
                red[8 + ni]   = fmaf(gC[reg], mv, red[8 + ni]);
                red[12 + ni]  = fmaf(uC[reg], mv, red[12 + ni]);
            }
        }
    }
#pragma unroll
    for (int i = 0; i < 16; ++i) {
        red[i] += __shfl_xor(red[i], 16);
        red[i] += __shfl_xor(red[i], 32);
    }
    if (lg == 0) {
#pragma unroll
        for (int ni = 0; ni < 4; ++ni) {
            const int n = ni * 16 + l15;
            sred[w][n]       = red[ni];
            sred[w][64 + n]  = red[4 + ni];
            sred[w][128 + n] = red[8 + ni];
            sred[w][192 + n] = red[12 + ni];
        }
    }
    __syncthreads();   // sred ready AND all MFMA reads of the w2b region complete

    {
        float* repl = acc_ws + (blockIdx.x & (NREP - 1)) * 4096;
        const int q = t >> 6, n = t & 63;
        const float v = sred[0][t] + sred[1][t] + sred[2][t] + sred[3][t];
        if (q == 0) atomicAdd(&repl[b * K + n], v);
        else        atomicAdd(&repl[1024 + (b * 3 + (q - 1)) * K + n], v);
    }

    // ---- m-tile: stage acc in LDS (reuse w2b region; stride 132), 512B-contiguous row stores ----
    float* mt = (float*)&lds[0];     // 64 rows x 132 floats = 33792 B
#pragma unroll
    for (int s = 0; s < 2; ++s)
#pragma unroll
        for (int ni = 0; ni < 4; ++ni) {
            const int n  = ni * 16 + l15;
            const int px = w * 32 + s * 16 + lg * 4;
            *(f32x4*)&mt[n * 132 + px] = acc[s][ni];
        }
    __syncthreads();

    float* mo = m_out + (size_t)b * K * HW + pb;
#pragma unroll
    for (int r = 0; r < 16; ++r) {
        const int n = w * 16 + r;
        const f32x2 v = *(const f32x2*)&mt[n * 132 + lane * 2];
        *(f32x2*)&mo[(size_t)n * HW + lane * 2] = v;
    }
}

// Kernel C: palette (sum NREP replicas, fused) + transformed = sum_k m * palette.
// 4 px/thread, f32x4. (v7 structure)
__global__ __launch_bounds__(256) void colorcnn_reconstruct(
    const float* __restrict__ m, const float* __restrict__ acc_ws,
    float* __restrict__ pal_out, float* __restrict__ t_out)
{
    __shared__ float pl[192];
    const int b    = blockIdx.x / 49;
    const int tile = blockIdx.x % 49;
    const int t    = threadIdx.x;

    if (t < 192) {
        const int c = t >> 6, k = t & 63;
        float dsum = 0.f, nsum = 0.f;
#pragma unroll
        for (int r = 0; r < NREP; ++r) {
            dsum += acc_ws[r * 4096 + b * K + k];
            nsum += acc_ws[r * 4096 + 1024 + (b * 3 + c) * K + k];
        }
        const float v = nsum / (dsum + 1e-8f);
        pl[t] = v;
        if (tile == 0) pal_out[b * 3 * K + t] = v;
    }
    __syncthreads();

    const int p = tile * 1024 + t * 4;
    const float* mp = m + (size_t)b * K * HW + p;
    f32x4 ar = {0.f, 0.f, 0.f, 0.f}, ag = ar, ab = ar;
#pragma unroll
    for (int k = 0; k < K; ++k) {
        const f32x4 mv = *(const f32x4*)&mp[(size_t)k * HW];
        const float pr = pl[k], pg = pl[K + k], pu = pl[2 * K + k];
#pragma unroll
        for (int j = 0; j < 4; ++j) {
            ar[j] = fmaf(mv[j], pr, ar[j]);
            ag[j] = fmaf(mv[j], pg, ag[j]);
            ab[j] = fmaf(mv[j], pu, ab[j]);
        }
    }
    float* to = t_out + (size_t)b * 3 * HW + p;
    *(f32x4*)&to[0]      = ar;
    *(f32x4*)&to[HW]     = ag;
    *(f32x4*)&to[2 * HW] = ab;
}

extern "C" void kernel_launch(void* const* d_in, const int* in_sizes, int n_in,
                              void* d_out, int out_size, void* d_ws, size_t ws_size,
                              hipStream_t stream) {
    const float* img = (const float*)d_in[0];
    const float* W1  = (const float*)d_in[1];
    const float* b1  = (const float*)d_in[2];
    const float* W2  = (const float*)d_in[3];

    float* out   = (float*)d_out;
    float* t_out = out + OUT_T_OFF;
    float* m_out = out + OUT_M_OFF;
    float* p_out = out + OUT_P_OFF;

    float*  wsf    = (float*)d_ws;
    float*  acc_ws = wsf + WS_ACC;
    float4* w1pp   = (float4*)(wsf + WS_W1P);
    ushort* w2b    = (ushort*)(wsf + WS_W2B);

    colorcnn_prep<<<NREP, 256, 0, stream>>>(W1, b1, W2, wsf, w1pp, w2b);
    colorcnn_mlp_softmax<<<dim3(HW / 128, BATCH), 256, 0, stream>>>(img, (const int4*)w1pp, w2b, m_out, acc_ws);
    colorcnn_reconstruct<<<BATCH * 49, 256, 0, stream>>>(m_out, acc_ws, p_out, t_out);
}

// Round 24
// 111.122 us; speedup vs baseline: 1.0430x; 1.0016x over previous
//
#include <hip/hip_runtime.h>
#include <hip/hip_bf16.h>

#define BATCH 16
#define HW 50176          // 224*224
#define HID 256
#define K 64
#define NREP 16           // den/num accumulator replicas

// output layout (floats): transformed [0, 2408448) | m [2408448, 53788672) | palette [53788672, +3072)
#define OUT_T_OFF 0
#define OUT_M_OFF 2408448
#define OUT_P_OFF 53788672

// workspace layout (floats):
//   acc replicas [0, 65536): NREP x { den[1024], num[3072] }
//   w1pp pair-packed float4 [65536, 66560)
//   w2b bf16 (16384 elems = 8192 floats) @ 66560
#define WS_ACC 0
#define WS_W1P 65536
#define WS_W2B 66560

typedef short bf16x8 __attribute__((ext_vector_type(8)));
typedef float f32x4  __attribute__((ext_vector_type(4)));
typedef float f32x2  __attribute__((ext_vector_type(2)));

static __device__ __forceinline__ ushort f2bf(float x) {
    union { __hip_bfloat16 h; ushort s; } u;
    u.h = __float2bfloat16(x);
    return u.s;
}

// Prep (16 blocks): block r zeroes replica r; blocks 0-7 convert a W2 slice to bf16;
// block 0 also packs W1+b1 as hid-PAIRS (SoA within pair).
__global__ __launch_bounds__(256) void colorcnn_prep(
    const float* __restrict__ W1, const float* __restrict__ b1,
    const float* __restrict__ W2, float* __restrict__ wsf,
    float4* __restrict__ w1pp, ushort* __restrict__ w2b)
{
    const int t = threadIdx.x;
    const int r = blockIdx.x;
    float* acc = wsf + WS_ACC + r * 4096;
#pragma unroll
    for (int q = 0; q < 16; ++q) acc[q * 256 + t] = 0.f;   // zero this replica
    if (r == 0) {
        const int q = t >> 1;
        if ((t & 1) == 0)
            w1pp[t] = make_float4(W1[6 * q + 0], W1[6 * q + 3], W1[6 * q + 1], W1[6 * q + 4]);
        else
            w1pp[t] = make_float4(W1[6 * q + 2], W1[6 * q + 5], b1[2 * q], b1[2 * q + 1]);
    }
    if (r < 8) {
#pragma unroll
        for (int q = 0; q < 8; ++q) {
            const int i = (r * 8 + q) * 256 + t;
            w2b[i] = f2bf(W2[i]);
        }
    }
}

// Kernel A: MLP via MFMA + softmax + den/num reduction (replicated atomics) + transposed m store.
// (v21/v23 body verbatim.)
__global__ __launch_bounds__(256, 4) void colorcnn_mlp_softmax(
    const float* __restrict__ img, const int4* __restrict__ w1pp4,
    const ushort* __restrict__ w2b, float* __restrict__ m_out,
    float* __restrict__ acc_ws)
{
    __shared__ int4 lds[2304];       // [0,2048): w2b swizzled, later reused as m-tile; [2048,2304): w1pp
    __shared__ float sred[4][256];   // per-wave den/num partials

    const int t = threadIdx.x;
    const int4* w2b16 = (const int4*)w2b;
#pragma unroll
    for (int q = 0; q < 8; ++q) {
        const int i = t + q * 256;
        const int n = i >> 5, s = i & 31;
        lds[n * 32 + (s ^ (n & 7))] = w2b16[i];
    }
    lds[2048 + t] = w1pp4[t];        // linear pair-packed
    __syncthreads();

    const int b    = blockIdx.y;
    const int pb   = blockIdx.x * 128;
    const int w    = t >> 6;
    const int lane = t & 63;
    const int l15  = lane & 15;
    const int lg   = lane >> 4;
    const int pwb  = pb + w * 32;
    const int x7   = l15 & 7;

    const float* ip = img + (size_t)b * 3 * HW;

    float rr[2], gg[2], uu[2];
#pragma unroll
    for (int s = 0; s < 2; ++s) {
        const int px = pwb + s * 16 + l15;
        rr[s] = ip[px]; gg[s] = ip[HW + px]; uu[s] = ip[2 * HW + px];
    }

    f32x4 acc[2][4];
#pragma unroll
    for (int s = 0; s < 2; ++s)
#pragma unroll
        for (int ni = 0; ni < 4; ++ni)
            acc[s][ni] = (f32x4){0.f, 0.f, 0.f, 0.f};

    const float4* w1base = (const float4*)&lds[2048 + lg * 8];

#pragma unroll
    for (int c = 0; c < 8; ++c) {
        union { bf16x8 v; unsigned int u[4]; } ua0, ua1;
#pragma unroll
        for (int p = 0; p < 4; ++p) {          // hid pair = c*16 + lg*4 + p
            const float4 uA = w1base[c * 32 + p * 2];       // {w0a,w0b,w1a,w1b}
            const float4 uB = w1base[c * 32 + p * 2 + 1];   // {w2a,w2b,ba,bb}
            const f32x2 wA0 = {uA.x, uA.y};
            const f32x2 wA1 = {uA.z, uA.w};
            const f32x2 wB0 = {uB.x, uB.y};
            const f32x2 bb2 = {uB.z, uB.w};
            const f32x2 z2  = {0.f, 0.f};

            f32x2 h0 = bb2, h1 = bb2;
            {
                const f32x2 r0 = {rr[0], rr[0]}, g0 = {gg[0], gg[0]}, u0 = {uu[0], uu[0]};
                h0 = r0 * wA0 + h0; h0 = g0 * wA1 + h0; h0 = u0 * wB0 + h0;
                h0 = __builtin_elementwise_max(h0, z2);
            }
            {
                const f32x2 r1 = {rr[1], rr[1]}, g1 = {gg[1], gg[1]}, u1 = {uu[1], uu[1]};
                h1 = r1 * wA0 + h1; h1 = g1 * wA1 + h1; h1 = u1 * wB0 + h1;
                h1 = __builtin_elementwise_max(h1, z2);
            }
            __hip_bfloat162 c0 = __float22bfloat162_rn(float2{h0.x, h0.y});
            __hip_bfloat162 c1 = __float22bfloat162_rn(float2{h1.x, h1.y});
            ua0.u[p] = *(unsigned int*)&c0;
            ua1.u[p] = *(unsigned int*)&c1;
        }
        const int sw = (c * 4 + lg) ^ x7;
#pragma unroll
        for (int ni = 0; ni < 4; ++ni) {
            const bf16x8 bf = *(const bf16x8*)&lds[(ni * 16 + l15) * 32 + sw];
            acc[0][ni] = __builtin_amdgcn_mfma_f32_16x16x32_bf16(ua0.v, bf, acc[0][ni], 0, 0, 0);
            acc[1][ni] = __builtin_amdgcn_mfma_f32_16x16x32_bf16(ua1.v, bf, acc[1][ni], 0, 0, 0);
        }
    }

    // Softmax over n=64 per pixel (no max-subtract; logits bounded, fp32 exp safe).
#pragma unroll
    for (int s = 0; s < 2; ++s) {
#pragma unroll
        for (int reg = 0; reg < 4; ++reg) {
            const float v0 = __expf(acc[s][0][reg]);
            const float v1 = __expf(acc[s][1][reg]);
            const float v2 = __expf(acc[s][2][reg]);
            const float v3 = __expf(acc[s][3][reg]);
            float sm = (v0 + v1) + (v2 + v3);
            sm += __shfl_xor(sm, 1);
            sm += __shfl_xor(sm, 2);
            sm += __shfl_xor(sm, 4);
            sm += __shfl_xor(sm, 8);
            const float inv = __builtin_amdgcn_rcpf(sm);
            acc[s][0][reg] = v0 * inv; acc[s][1][reg] = v1 * inv;
            acc[s][2][reg] = v2 * inv; acc[s][3][reg] = v3 * inv;
        }
    }

    // ---- den/num reduction ----
    float red[16];   // [q*4+ni], q: 0=den 1=numR 2=numG 3=numB ; n = ni*16 + l15
#pragma unroll
    for (int i = 0; i < 16; ++i) red[i] = 0.f;
#pragma unroll
    for (int s = 0; s < 2; ++s) {
        const int pxb = pwb + s * 16 + lg * 4;
        const f32x4 rC = *(const f32x4*)&ip[pxb];
        const f32x4 gC = *(const f32x4*)&ip[HW + pxb];
        const f32x4 uC = *(const f32x4*)&ip[2 * HW + pxb];
#pragma unroll
        for (int ni = 0; ni < 4; ++ni) {
#pragma unroll
            for (int reg = 0; reg < 4; ++reg) {
                const float mv = acc[s][ni][reg];
                red[ni]      += mv;
                red[4 + ni]   = fmaf(rC[reg], mv, red[4 + ni]);
                red[8 + ni]   = fmaf(gC[reg], mv, red[8 + ni]);
                red[12 + ni]  = fmaf(uC[reg], mv, red[12 + ni]);
            }
        }
    }
#pragma unroll
    for (int i = 0; i < 16; ++i) {
        red[i] += __shfl_xor(red[i], 16);
        red[i] += __shfl_xor(red[i], 32);
    }
    if (lg == 0) {
#pragma unroll
        for (int ni = 0; ni < 4; ++ni) {
            const int n = ni * 16 + l15;
            sred[w][n]       = red[ni];
            sred[w][64 + n]  = red[4 + ni];
            sred[w][128 + n] = red[8 + ni];
            sred[w][192 + n] = red[12 + ni];
        }
    }
    __syncthreads();   // sred ready AND all MFMA reads of the w2b region complete

    {
        float* repl = acc_ws + (blockIdx.x & (NREP - 1)) * 4096;
        const int q = t >> 6, n = t & 63;
        const float v = sred[0][t] + sred[1][t] + sred[2][t] + sred[3][t];
        if (q == 0) atomicAdd(&repl[b * K + n], v);
        else        atomicAdd(&repl[1024 + (b * 3 + (q - 1)) * K + n], v);
    }

    // ---- m-tile: stage acc in LDS (reuse w2b region; stride 132), 512B-contiguous row stores ----
    float* mt = (float*)&lds[0];     // 64 rows x 132 floats = 33792 B
#pragma unroll
    for (int s = 0; s < 2; ++s)
#pragma unroll
        for (int ni = 0; ni < 4; ++ni) {
            const int n  = ni * 16 + l15;
            const int px = w * 32 + s * 16 + lg * 4;
            *(f32x4*)&mt[n * 132 + px] = acc[s][ni];
        }
    __syncthreads();

    float* mo = m_out + (size_t)b * K * HW + pb;
#pragma unroll
    for (int r = 0; r < 16; ++r) {
        const int n = w * 16 + r;
        const f32x2 v = *(const f32x2*)&mt[n * 132 + lane * 2];
        *(f32x2*)&mo[(size_t)n * HW + lane * 2] = v;
    }
}

// Kernel C: palette (sum NREP replicas, fused) + transformed = sum_k m * palette.
// 2 px/thread, 1568 blocks (~6.1 blocks/CU — clean TLP A/B vs v23's 784-block/4px config).
__global__ __launch_bounds__(256) void colorcnn_reconstruct(
    const float* __restrict__ m, const float* __restrict__ acc_ws,
    float* __restrict__ pal_out, float* __restrict__ t_out)
{
    __shared__ float pl[192];
    const int b    = blockIdx.y;
    const int tile = blockIdx.x;
    const int t    = threadIdx.x;

    if (t < 192) {
        const int c = t >> 6, k = t & 63;
        float dsum = 0.f, nsum = 0.f;
#pragma unroll
        for (int r = 0; r < NREP; ++r) {
            dsum += acc_ws[r * 4096 + b * K + k];
            nsum += acc_ws[r * 4096 + 1024 + (b * 3 + c) * K + k];
        }
        const float v = nsum / (dsum + 1e-8f);
        pl[t] = v;
        if (tile == 0) pal_out[b * 3 * K + t] = v;
    }
    __syncthreads();

    const int p = tile * 512 + t * 2;
    const float* mp = m + (size_t)b * K * HW + p;
    f32x2 ar = {0.f, 0.f}, ag = ar, ab = ar;
#pragma unroll
    for (int k = 0; k < K; ++k) {
        const f32x2 mv = *(const f32x2*)&mp[(size_t)k * HW];
        const float pr = pl[k], pg = pl[K + k], pu = pl[2 * K + k];
#pragma unroll
        for (int j = 0; j < 2; ++j) {
            ar[j] = fmaf(mv[j], pr, ar[j]);
            ag[j] = fmaf(mv[j], pg, ag[j]);
            ab[j] = fmaf(mv[j], pu, ab[j]);
        }
    }
    float* to = t_out + (size_t)b * 3 * HW + p;
    *(f32x2*)&to[0]      = ar;
    *(f32x2*)&to[HW]     = ag;
    *(f32x2*)&to[2 * HW] = ab;
}

extern "C" void kernel_launch(void* const* d_in, const int* in_sizes, int n_in,
                              void* d_out, int out_size, void* d_ws, size_t ws_size,
                              hipStream_t stream) {
    const float* img = (const float*)d_in[0];
    const float* W1  = (const float*)d_in[1];
    const float* b1  = (const float*)d_in[2];
    const float* W2  = (const float*)d_in[3];

    float* out   = (float*)d_out;
    float* t_out = out + OUT_T_OFF;
    float* m_out = out + OUT_M_OFF;
    float* p_out = out + OUT_P_OFF;

    float*  wsf    = (float*)d_ws;
    float*  acc_ws = wsf + WS_ACC;
    float4* w1pp   = (float4*)(wsf + WS_W1P);
    ushort* w2b    = (ushort*)(wsf + WS_W2B);

    colorcnn_prep<<<NREP, 256, 0, stream>>>(W1, b1, W2, wsf, w1pp, w2b);
    colorcnn_mlp_softmax<<<dim3(HW / 128, BATCH), 256, 0, stream>>>(img, (const int4*)w1pp, w2b, m_out, acc_ws);
    colorcnn_reconstruct<<<dim3(HW / 512, BATCH), 256, 0, stream>>>(m_out, acc_ws, p_out, t_out);
}